// Round 2
// baseline (301.518 us; speedup 1.0000x reference)
//
#include <hip/hip_runtime.h>
#include <stdint.h>

// ---------------------------------------------------------------------------
// BailingMoE block: T=1024, H=1024, E=16, top-4, I=512 routed, Is=1024 shared
// R2: fused phase kernels, 64x(64G+64U) wave tiles, BK=64 XOR-swizzled LDS,
// global_load_lds(16B) weight staging, atomic-free combine.
// ---------------------------------------------------------------------------

typedef __attribute__((ext_vector_type(8))) unsigned short ushort8;
typedef __attribute__((ext_vector_type(4))) float f32x4;
typedef __attribute__((ext_vector_type(8))) __bf16 bf16x8;

#define T_TOK 1024
#define HID   1024
#define NEXP  16
#define TOPK  4
#define MINTER 512
#define SINTER 1024

// ws byte offsets (same footprint as R1; R overlays dead WgT/WuT in phase 2)
constexpr size_t OFF_COUNTS = 0;                               // 16 ints
constexpr size_t OFF_LIST   = 1024;                            // 16*1024 ints
constexpr size_t OFF_WT     = OFF_LIST  + 65536;               // 16*1024 floats
constexpr size_t OFF_TIDX   = OFF_WT    + 65536;               // 4096 ints
constexpr size_t OFF_XB     = OFF_TIDX  + 65536;               // bf16 1024x1024
constexpr size_t OFF_HS     = OFF_XB    + 2097152;             // bf16 1024x1024
constexpr size_t OFF_HR     = OFF_HS    + 2097152;             // bf16 4096x512 compact
constexpr size_t OFF_WGT    = OFF_HR    + 4194304;             // bf16 16x512x1024
constexpr size_t OFF_WUT    = OFF_WGT   + 16777216;            // bf16 16x512x1024
constexpr size_t OFF_WDT    = OFF_WUT   + 16777216;            // bf16 16x1024x512
constexpr size_t OFF_WSGUT  = OFF_WDT   + 16777216;            // bf16 2048x1024
constexpr size_t OFF_WSDT   = OFF_WSGUT + 4194304;             // bf16 1024x1024
constexpr size_t OFF_ROUT   = OFF_WGT;                         // fp32 4096x1024 (overlay)

__device__ __forceinline__ unsigned short f2bf(float f) {
  union { float f; uint32_t u; } v; v.f = f;
  uint32_t r = (v.u + 0x7FFFu + ((v.u >> 16) & 1u)) >> 16;
  return (unsigned short)r;
}
__device__ __forceinline__ bf16x8 as_bf16x8(ushort8 s) {
  union { ushort8 s; bf16x8 b; } u; u.s = s; return u.b;
}
__device__ __forceinline__ float silu(float g) { return g / (1.f + __expf(-g)); }

// async global->LDS, 16B per lane; lds dest must be wave-uniform base, lane
// data lands at base + lane*16 (m104/m108).
__device__ __forceinline__ void glds16(const unsigned short* g, unsigned short* l) {
  __builtin_amdgcn_global_load_lds(
      (const __attribute__((address_space(1))) unsigned int*)g,
      (__attribute__((address_space(3))) unsigned int*)l, 16, 0, 0);
}

// -------------------------- init: zero expert counts -----------------------
__global__ void init_kernel(int* counts) {
  if (threadIdx.x < NEXP) counts[threadIdx.x] = 0;
}

// -------------------------- router: fp32, one wave per token ---------------
__global__ __launch_bounds__(64) void router_kernel(
    const float* __restrict__ x, const float* __restrict__ rw,
    int* counts, int* list, float* wt, int* tIdx) {
  const int t = blockIdx.x, l = threadIdx.x;
  float xv[16];
#pragma unroll
  for (int j = 0; j < 16; j++) xv[j] = x[t * HID + j * 64 + l];
  float p[NEXP];
#pragma unroll
  for (int e = 0; e < NEXP; e++) {
    float s = 0.f;
#pragma unroll
    for (int j = 0; j < 16; j++) s += xv[j] * rw[e * HID + j * 64 + l];
#pragma unroll
    for (int off = 32; off > 0; off >>= 1) s += __shfl_xor(s, off);
    p[e] = s;
  }
  float mx = p[0];
#pragma unroll
  for (int e = 1; e < NEXP; e++) mx = fmaxf(mx, p[e]);
  int idx[TOPK]; float w4[TOPK]; float wsum = 0.f; unsigned used = 0u;
#pragma unroll
  for (int k = 0; k < TOPK; k++) {
    float bv = -1e30f; int bi = 0;
#pragma unroll
    for (int e = 0; e < NEXP; e++)
      if (!((used >> e) & 1u) && p[e] > bv) { bv = p[e]; bi = e; }
    used |= 1u << bi;
    idx[k] = bi;
    w4[k] = __expf(p[bi] - mx);
    wsum += w4[k];
  }
  const float inv = 1.f / wsum;  // softmax denom cancels under top-k renorm
  if (l < TOPK) {
    const int e = idx[l];
    const int pos = atomicAdd(&counts[e], 1);
    list[e * 1024 + pos] = t;
    wt[e * 1024 + pos]   = w4[l] * inv;
    tIdx[t * TOPK + l]   = (e << 10) | pos;
  }
}

// -------------------------- fp32 -> bf16 convert (x) -----------------------
__global__ void convert_bf16_kernel(const float* __restrict__ src,
                                    unsigned short* __restrict__ dst, int n) {
  const int i = (blockIdx.x * blockDim.x + threadIdx.x) * 4;
  if (i + 3 < n) {
    const float4 v = *(const float4*)(src + i);
    dst[i + 0] = f2bf(v.x); dst[i + 1] = f2bf(v.y);
    dst[i + 2] = f2bf(v.z); dst[i + 3] = f2bf(v.w);
  }
}

// ------------------ batched transpose + convert: [b][R][C] -> [b][C][R] ----
__global__ __launch_bounds__(256) void transpose64_kernel(
    const float* __restrict__ src, unsigned short* __restrict__ dst,
    int R, int C) {
  __shared__ float tile[64][65];
  const size_t bo = (size_t)blockIdx.z * R * C;
  const int c0 = blockIdx.x * 64, r0 = blockIdx.y * 64, t = threadIdx.x;
  {
    const int r = t >> 4, c4 = (t & 15) * 4;
#pragma unroll
    for (int p = 0; p < 4; p++) {
      const int rr = p * 16 + r;
      const float4 v = *(const float4*)(src + bo + (size_t)(r0 + rr) * C + c0 + c4);
      tile[rr][c4 + 0] = v.x; tile[rr][c4 + 1] = v.y;
      tile[rr][c4 + 2] = v.z; tile[rr][c4 + 3] = v.w;
    }
  }
  __syncthreads();
  {
    const int c = t >> 2, rb = (t & 3) * 16;
#pragma unroll
    for (int s = 0; s < 4; s++) {
      const int rr = rb + 4 * s;
      union { unsigned short u[4]; uint2 v; } pk;
#pragma unroll
      for (int i = 0; i < 4; i++) pk.u[i] = f2bf(tile[rr + i][c]);
      *(uint2*)(dst + bo + (size_t)(c0 + c) * R + r0 + rr) = pk.v;
    }
  }
}

// ---------------------------------------------------------------------------
// Phase 1: gate/up for routed (z<16) and shared (z==16) experts.
// Block: 256 thr = 4 waves in 2x2; block tile M=128 x N=128 cols (G and U).
// Wave tile: 64 rows x 64 cols, both G and U (A-frag reuse).
// LDS: sA 128x64 bf16 (16KB), sB 256x64 bf16 (32KB: rows 0-127 G, 128-255 U).
// Row = 128B; chunk c in [0,8); data of global chunk g at c = g ^ (row&7):
// all ds_read_b128/ds_write_b128 land 8 lanes per 4-bank group (free).
// ---------------------------------------------------------------------------
__global__ __launch_bounds__(256, 2) void phase1_kernel(
    const unsigned short* __restrict__ Xb,
    const unsigned short* __restrict__ WgT,   // [16][512][1024]
    const unsigned short* __restrict__ WuT,   // [16][512][1024]
    const unsigned short* __restrict__ WsguT, // [2048][1024]
    const int* __restrict__ counts, const int* __restrict__ list,
    const float* __restrict__ wt,
    unsigned short* __restrict__ Hr,          // [4096][512] compact
    unsigned short* __restrict__ Hs) {        // [1024][1024]
  const int z = blockIdx.z, x = blockIdx.x, y = blockIdx.y;
  const bool routed = (z < NEXP);
  int cnt = 0, base = 0;
  if (routed) {
    if (x >= 4) return;                       // routed N=512 -> 4 x-blocks
    cnt = counts[z];
    if (y * 128 >= cnt) return;
#pragma unroll
    for (int i = 0; i < NEXP; i++) base += (i < z) ? counts[i] : 0;
  }
  __shared__ __align__(16) unsigned short sA[128 * 64];
  __shared__ __align__(16) unsigned short sB[256 * 64];
  const int tid = threadIdx.x, w = tid >> 6, l = tid & 63;
  const int wm = w >> 1, wn = w & 1, m0 = y * 128;

  // A staging pointers: thread covers row r = tid>>1, lds chunks p=(tid&1)*4+c
  const int ar = tid >> 1;
  const unsigned short* aRow;
  if (routed) {
    const int pos = min(m0 + ar, cnt - 1);
    aRow = Xb + (size_t)list[z * 1024 + pos] * HID;
  } else {
    aRow = Xb + (size_t)(m0 + ar) * HID;
  }
  const unsigned short* aptr[4];
  int aoff[4];
#pragma unroll
  for (int c = 0; c < 4; c++) {
    const int p = (tid & 1) * 4 + c;
    aptr[c] = aRow + ((p ^ (ar & 7)) * 8);
    aoff[c] = ar * 64 + p * 8;
  }
  // B staging pointers: wave w stages sB rows 64w..64w+63, 8 glds instrs
  const unsigned short* bptr[8];
#pragma unroll
  for (int i = 0; i < 8; i++) {
    const int R = 64 * w + 8 * i + (l >> 3);
    const int g = (l & 7) ^ (R & 7);
    const unsigned short* rowp;
    if (routed) {
      const int col = x * 128 + (R & 127);
      rowp = ((R >> 7) ? WuT : WgT) + (size_t)z * MINTER * HID + (size_t)col * HID;
    } else {
      const int col = x * 128 + (R & 127);
      rowp = WsguT + (size_t)((R >> 7) * SINTER + col) * HID;
    }
    bptr[i] = rowp + g * 8;
  }

  f32x4 accG[4][4], accU[4][4];
#pragma unroll
  for (int i = 0; i < 4; i++)
#pragma unroll
    for (int j = 0; j < 4; j++) {
      accG[i][j] = (f32x4){0.f, 0.f, 0.f, 0.f};
      accU[i][j] = (f32x4){0.f, 0.f, 0.f, 0.f};
    }

  for (int k0 = 0; k0 < HID; k0 += 64) {
    ushort8 av[4];
#pragma unroll
    for (int c = 0; c < 4; c++) av[c] = *(const ushort8*)(aptr[c] + k0);
    __syncthreads();
#pragma unroll
    for (int c = 0; c < 4; c++) *(ushort8*)(sA + aoff[c]) = av[c];
#pragma unroll
    for (int i = 0; i < 8; i++)
      glds16(bptr[i] + k0, sB + (64 * w + 8 * i) * 64);
    __syncthreads();
#pragma unroll
    for (int h = 0; h < 2; h++) {
      const int pc = ((h * 4 + (l >> 4)) ^ (l & 7)) * 8;
      bf16x8 af[4];
#pragma unroll
      for (int i = 0; i < 4; i++)
        af[i] = as_bf16x8(*(const ushort8*)(sA + (wm * 64 + 16 * i + (l & 15)) * 64 + pc));
#pragma unroll
      for (int j = 0; j < 4; j++) {
        const int Rg = wn * 64 + 16 * j + (l & 15);
        const bf16x8 gf = as_bf16x8(*(const ushort8*)(sB + Rg * 64 + pc));
        const bf16x8 uf = as_bf16x8(*(const ushort8*)(sB + (128 + Rg) * 64 + pc));
#pragma unroll
        for (int i = 0; i < 4; i++) {
          accG[i][j] = __builtin_amdgcn_mfma_f32_16x16x32_bf16(af[i], gf, accG[i][j], 0, 0, 0);
          accU[i][j] = __builtin_amdgcn_mfma_f32_16x16x32_bf16(af[i], uf, accU[i][j], 0, 0, 0);
        }
      }
    }
  }

  // epilogue: C/D map col=lane&15, row=(lane>>4)*4+reg
#pragma unroll
  for (int i = 0; i < 4; i++)
#pragma unroll
    for (int r = 0; r < 4; r++) {
      const int row = wm * 64 + 16 * i + (l >> 4) * 4 + r;
      const int grow = m0 + row;
      if (routed) {
        if (grow < cnt) {
          const float wrow = wt[z * 1024 + grow];
#pragma unroll
          for (int j = 0; j < 4; j++) {
            const int col = x * 128 + wn * 64 + 16 * j + (l & 15);
            const float h = silu(accG[i][j][r]) * accU[i][j][r] * wrow;
            Hr[(size_t)(base + grow) * MINTER + col] = f2bf(h);
          }
        }
      } else {
#pragma unroll
        for (int j = 0; j < 4; j++) {
          const int col = x * 128 + wn * 64 + 16 * j + (l & 15);
          const float h = silu(accG[i][j][r]) * accU[i][j][r];
          Hs[(size_t)grow * SINTER + col] = f2bf(h);
        }
      }
    }
}

// ---------------------------------------------------------------------------
// Phase 2: down-proj. z<16 routed (K=512, plain stores to compact Rout),
// z==16 shared (K=1024, stores to out). Wave tile 64 x 128, block 128 x 256.
// ---------------------------------------------------------------------------
__global__ __launch_bounds__(256, 2) void phase2_kernel(
    const unsigned short* __restrict__ Hr, const unsigned short* __restrict__ Hs,
    const unsigned short* __restrict__ WdT,  // [16][1024][512]
    const unsigned short* __restrict__ WsdT, // [1024][1024]
    const int* __restrict__ counts,
    float* __restrict__ Rout,                // [4096][1024] compact
    float* __restrict__ out) {               // [1024][1024]
  const int z = blockIdx.z, x = blockIdx.x, y = blockIdx.y;
  const bool routed = (z < NEXP);
  int cnt = 0, base = 0, kdim;
  if (routed) {
    cnt = counts[z];
    if (y * 128 >= cnt) return;
#pragma unroll
    for (int i = 0; i < NEXP; i++) base += (i < z) ? counts[i] : 0;
    kdim = MINTER;
  } else {
    kdim = SINTER;
  }
  __shared__ __align__(16) unsigned short sA[128 * 64];
  __shared__ __align__(16) unsigned short sB[256 * 64];
  const int tid = threadIdx.x, w = tid >> 6, l = tid & 63;
  const int wm = w >> 1, wn = w & 1, m0 = y * 128;

  const int ar = tid >> 1;
  const unsigned short* aRow;
  if (routed) {
    const int pos = min(m0 + ar, cnt - 1);
    aRow = Hr + (size_t)(base + pos) * MINTER;
  } else {
    aRow = Hs + (size_t)(m0 + ar) * SINTER;
  }
  const unsigned short* aptr[4];
  int aoff[4];
#pragma unroll
  for (int c = 0; c < 4; c++) {
    const int p = (tid & 1) * 4 + c;
    aptr[c] = aRow + ((p ^ (ar & 7)) * 8);
    aoff[c] = ar * 64 + p * 8;
  }
  const unsigned short* bptr[8];
#pragma unroll
  for (int i = 0; i < 8; i++) {
    const int R = 64 * w + 8 * i + (l >> 3);
    const int g = (l & 7) ^ (R & 7);
    const int col = x * 256 + R;
    const unsigned short* rowp =
        routed ? (WdT + (size_t)z * HID * MINTER + (size_t)col * MINTER)
               : (WsdT + (size_t)col * SINTER);
    bptr[i] = rowp + g * 8;
  }

  f32x4 acc[4][8];
#pragma unroll
  for (int i = 0; i < 4; i++)
#pragma unroll
    for (int j = 0; j < 8; j++) acc[i][j] = (f32x4){0.f, 0.f, 0.f, 0.f};

  for (int k0 = 0; k0 < kdim; k0 += 64) {
    ushort8 av[4];
#pragma unroll
    for (int c = 0; c < 4; c++) av[c] = *(const ushort8*)(aptr[c] + k0);
    __syncthreads();
#pragma unroll
    for (int c = 0; c < 4; c++) *(ushort8*)(sA + aoff[c]) = av[c];
#pragma unroll
    for (int i = 0; i < 8; i++)
      glds16(bptr[i] + k0, sB + (64 * w + 8 * i) * 64);
    __syncthreads();
#pragma unroll
    for (int h = 0; h < 2; h++) {
      const int pc = ((h * 4 + (l >> 4)) ^ (l & 7)) * 8;
      bf16x8 af[4];
#pragma unroll
      for (int i = 0; i < 4; i++)
        af[i] = as_bf16x8(*(const ushort8*)(sA + (wm * 64 + 16 * i + (l & 15)) * 64 + pc));
#pragma unroll
      for (int j = 0; j < 8; j++) {
        const int Rb = wn * 128 + 16 * j + (l & 15);
        const bf16x8 bfv = as_bf16x8(*(const ushort8*)(sB + Rb * 64 + pc));
#pragma unroll
        for (int i = 0; i < 4; i++)
          acc[i][j] = __builtin_amdgcn_mfma_f32_16x16x32_bf16(af[i], bfv, acc[i][j], 0, 0, 0);
      }
    }
  }

#pragma unroll
  for (int i = 0; i < 4; i++)
#pragma unroll
    for (int r = 0; r < 4; r++) {
      const int row = wm * 64 + 16 * i + (l >> 4) * 4 + r;
      const int grow = m0 + row;
      if (routed) {
        if (grow < cnt) {
#pragma unroll
          for (int j = 0; j < 8; j++) {
            const int col = x * 256 + wn * 128 + 16 * j + (l & 15);
            Rout[(size_t)(base + grow) * HID + col] = acc[i][j][r];
          }
        }
      } else {
#pragma unroll
        for (int j = 0; j < 8; j++) {
          const int col = x * 256 + wn * 128 + 16 * j + (l & 15);
          out[(size_t)grow * HID + col] = acc[i][j][r];
        }
      }
    }
}

// ------------- combine: out[t] += sum_k Rout[base[e_k]+pos_k] --------------
__global__ __launch_bounds__(256) void combine_kernel(
    const float* __restrict__ Rout, const int* __restrict__ counts,
    const int* __restrict__ tIdx, float* __restrict__ out) {
  __shared__ int sb[NEXP];
  if (threadIdx.x == 0) {
    int s = 0;
#pragma unroll
    for (int e = 0; e < NEXP; e++) { sb[e] = s; s += counts[e]; }
  }
  __syncthreads();
  const int t = blockIdx.x, c4 = threadIdx.x * 4;
  float4 o = *(const float4*)(out + (size_t)t * HID + c4);
#pragma unroll
  for (int k = 0; k < TOPK; k++) {
    const int v = tIdx[t * TOPK + k];
    const int row = sb[v >> 10] + (v & 1023);
    const float4 rv = *(const float4*)(Rout + (size_t)row * HID + c4);
    o.x += rv.x; o.y += rv.y; o.z += rv.z; o.w += rv.w;
  }
  *(float4*)(out + (size_t)t * HID + c4) = o;
}

// ---------------------------------------------------------------------------
extern "C" void kernel_launch(void* const* d_in, const int* in_sizes, int n_in,
                              void* d_out, int out_size, void* d_ws, size_t ws_size,
                              hipStream_t stream) {
  const float* x      = (const float*)d_in[0];
  const float* rw     = (const float*)d_in[1];
  const float* w_gate = (const float*)d_in[2];
  const float* w_up   = (const float*)d_in[3];
  const float* w_down = (const float*)d_in[4];
  const float* ws_gu  = (const float*)d_in[5];
  const float* ws_dn  = (const float*)d_in[6];
  float* out = (float*)d_out;
  char* ws = (char*)d_ws;

  int*   counts = (int*)  (ws + OFF_COUNTS);
  int*   list   = (int*)  (ws + OFF_LIST);
  float* wtbuf  = (float*)(ws + OFF_WT);
  int*   tIdx   = (int*)  (ws + OFF_TIDX);
  unsigned short* Xb    = (unsigned short*)(ws + OFF_XB);
  unsigned short* Hs    = (unsigned short*)(ws + OFF_HS);
  unsigned short* Hr    = (unsigned short*)(ws + OFF_HR);
  unsigned short* WgT   = (unsigned short*)(ws + OFF_WGT);
  unsigned short* WuT   = (unsigned short*)(ws + OFF_WUT);
  unsigned short* WdT   = (unsigned short*)(ws + OFF_WDT);
  unsigned short* WsguT = (unsigned short*)(ws + OFF_WSGUT);
  unsigned short* WsdT  = (unsigned short*)(ws + OFF_WSDT);
  float* Rout = (float*)(ws + OFF_ROUT);   // overlays WgT/WuT (dead in phase 2)

  init_kernel<<<1, 64, 0, stream>>>(counts);
  router_kernel<<<T_TOK, 64, 0, stream>>>(x, rw, counts, list, wtbuf, tIdx);
  convert_bf16_kernel<<<1024, 256, 0, stream>>>(x, Xb, T_TOK * HID);
  // weights: [b][R][C] fp32 -> [b][C][R] bf16 (k-contiguous for MFMA B-op)
  transpose64_kernel<<<dim3(8, 16, 16), 256, 0, stream>>>(w_gate, WgT, HID, MINTER);
  transpose64_kernel<<<dim3(8, 16, 16), 256, 0, stream>>>(w_up,   WuT, HID, MINTER);
  transpose64_kernel<<<dim3(16, 8, 16), 256, 0, stream>>>(w_down, WdT, MINTER, HID);
  transpose64_kernel<<<dim3(32, 16, 1), 256, 0, stream>>>(ws_gu,  WsguT, HID, 2 * SINTER);
  transpose64_kernel<<<dim3(16, 16, 1), 256, 0, stream>>>(ws_dn,  WsdT, SINTER, HID);
  // phase 1: all gate/up (routed z<16 over x<4,y<ceil(cnt/128); shared z=16)
  phase1_kernel<<<dim3(8, 8, 17), 256, 0, stream>>>(
      Xb, WgT, WuT, WsguT, counts, list, wtbuf, Hr, Hs);
  // phase 2: all down-proj (routed -> Rout, shared -> out)
  phase2_kernel<<<dim3(4, 8, 17), 256, 0, stream>>>(
      Hr, Hs, WdT, WsdT, counts, Rout, out);
  combine_kernel<<<T_TOK, 256, 0, stream>>>(Rout, counts, tIdx, out);
  (void)in_sizes; (void)n_in; (void)out_size; (void)ws_size;
}

// Round 3
// 296.261 us; speedup vs baseline: 1.0177x; 1.0177x over previous
//
#include <hip/hip_runtime.h>
#include <stdint.h>

// ---------------------------------------------------------------------------
// BailingMoE block: T=1024, H=1024, E=16, top-4, I=512 routed, Is=1024 shared
// R3: single-barrier double-buffered K-loops (glds16 prefetch for A and B),
// BK=32, merged transpose pass, router-fused x->bf16, bf16 Rout combine.
// ---------------------------------------------------------------------------

typedef __attribute__((ext_vector_type(8))) unsigned short ushort8;
typedef __attribute__((ext_vector_type(4))) float f32x4;
typedef __attribute__((ext_vector_type(8))) __bf16 bf16x8;

#define T_TOK 1024
#define HID   1024
#define NEXP  16
#define TOPK  4
#define MINTER 512
#define SINTER 1024

constexpr size_t OFF_COUNTS = 0;                               // 16 ints
constexpr size_t OFF_LIST   = 1024;                            // 16*1024 ints
constexpr size_t OFF_WT     = OFF_LIST  + 65536;               // 16*1024 floats
constexpr size_t OFF_TIDX   = OFF_WT    + 65536;               // 4096 ints
constexpr size_t OFF_XB     = OFF_TIDX  + 65536;               // bf16 1024x1024
constexpr size_t OFF_HS     = OFF_XB    + 2097152;             // bf16 1024x1024
constexpr size_t OFF_HR     = OFF_HS    + 2097152;             // bf16 4096x512 compact
constexpr size_t OFF_WGT    = OFF_HR    + 4194304;             // bf16 16x512x1024
constexpr size_t OFF_WUT    = OFF_WGT   + 16777216;            // bf16 16x512x1024
constexpr size_t OFF_WDT    = OFF_WUT   + 16777216;            // bf16 16x1024x512
constexpr size_t OFF_WSGUT  = OFF_WDT   + 16777216;            // bf16 2048x1024
constexpr size_t OFF_WSDT   = OFF_WSGUT + 4194304;             // bf16 1024x1024
constexpr size_t OFF_ROUT   = OFF_WGT;   // bf16 4096x1024 overlay (WgT dead in phase2)

__device__ __forceinline__ unsigned short f2bf(float f) {
  union { float f; uint32_t u; } v; v.f = f;
  uint32_t r = (v.u + 0x7FFFu + ((v.u >> 16) & 1u)) >> 16;
  return (unsigned short)r;
}
__device__ __forceinline__ float bfu2f(uint32_t u) {
  union { uint32_t u; float f; } v; v.u = u << 16; return v.f;
}
__device__ __forceinline__ bf16x8 as_bf16x8(ushort8 s) {
  union { ushort8 s; bf16x8 b; } u; u.s = s; return u.b;
}
__device__ __forceinline__ float silu(float g) { return g / (1.f + __expf(-g)); }

// async global->LDS, 16B/lane. Per-lane global addr is free-form; LDS dest is
// wave-uniform base, lane data lands at base + lane*16 (m104/m108).
__device__ __forceinline__ void glds16(const unsigned short* g, unsigned short* l) {
  __builtin_amdgcn_global_load_lds(
      (const __attribute__((address_space(1))) unsigned int*)g,
      (__attribute__((address_space(3))) unsigned int*)l, 16, 0, 0);
}

// -------------------------- init: zero expert counts -----------------------
__global__ void init_kernel(int* counts) {
  if (threadIdx.x < NEXP) counts[threadIdx.x] = 0;
}

// ------------- router (fp32, one wave/token) + fused x->bf16 write ---------
__global__ __launch_bounds__(64) void router_kernel(
    const float* __restrict__ x, const float* __restrict__ rw,
    int* counts, int* list, float* wt, int* tIdx,
    unsigned short* __restrict__ Xb) {
  const int t = blockIdx.x, l = threadIdx.x;
  float xv[16];
#pragma unroll
  for (int j = 0; j < 16; j++) xv[j] = x[t * HID + j * 64 + l];
#pragma unroll
  for (int j = 0; j < 16; j++) Xb[t * HID + j * 64 + l] = f2bf(xv[j]);
  float p[NEXP];
#pragma unroll
  for (int e = 0; e < NEXP; e++) {
    float s = 0.f;
#pragma unroll
    for (int j = 0; j < 16; j++) s += xv[j] * rw[e * HID + j * 64 + l];
#pragma unroll
    for (int off = 32; off > 0; off >>= 1) s += __shfl_xor(s, off);
    p[e] = s;
  }
  float mx = p[0];
#pragma unroll
  for (int e = 1; e < NEXP; e++) mx = fmaxf(mx, p[e]);
  int idx[TOPK]; float w4[TOPK]; float wsum = 0.f; unsigned used = 0u;
#pragma unroll
  for (int k = 0; k < TOPK; k++) {
    float bv = -1e30f; int bi = 0;
#pragma unroll
    for (int e = 0; e < NEXP; e++)
      if (!((used >> e) & 1u) && p[e] > bv) { bv = p[e]; bi = e; }
    used |= 1u << bi;
    idx[k] = bi;
    w4[k] = __expf(p[bi] - mx);
    wsum += w4[k];
  }
  const float inv = 1.f / wsum;  // softmax denom cancels under top-k renorm
  if (l < TOPK) {
    const int e = idx[l];
    const int pos = atomicAdd(&counts[e], 1);
    list[e * 1024 + pos] = t;
    wt[e * 1024 + pos]   = w4[l] * inv;
    tIdx[t * TOPK + l]   = (e << 10) | pos;
  }
}

// ---------------- one dispatch: all 5 weight transposes (fp32->bf16) -------
__global__ __launch_bounds__(256) void transpose_all_kernel(
    const float* __restrict__ Wg, const float* __restrict__ Wu,
    const float* __restrict__ Wd, const float* __restrict__ Wsgu,
    const float* __restrict__ Wsd,
    unsigned short* __restrict__ WgT, unsigned short* __restrict__ WuT,
    unsigned short* __restrict__ WdT, unsigned short* __restrict__ WsguT,
    unsigned short* __restrict__ WsdT) {
  const int bid = blockIdx.x;
  const float* src; unsigned short* dst; int R, C, tx, ty; size_t bo;
  if (bid < 4096) {                    // Wg/Wu: [16][1024][512]
    const int which = bid >> 11, loc = bid & 2047;
    const int b = loc >> 7, t8 = loc & 127;
    src = which ? Wu : Wg; dst = which ? WuT : WgT;
    R = 1024; C = 512; bo = (size_t)b * R * C;
    tx = t8 & 7; ty = t8 >> 3;
  } else if (bid < 6144) {             // Wd: [16][512][1024]
    const int loc = bid - 4096, b = loc >> 7, t8 = loc & 127;
    src = Wd; dst = WdT; R = 512; C = 1024; bo = (size_t)b * R * C;
    tx = t8 & 15; ty = t8 >> 4;
  } else if (bid < 6656) {             // Wsgu: [1024][2048]
    const int loc = bid - 6144;
    src = Wsgu; dst = WsguT; R = 1024; C = 2048; bo = 0;
    tx = loc & 31; ty = loc >> 5;
  } else {                             // Wsd: [1024][1024]
    const int loc = bid - 6656;
    src = Wsd; dst = WsdT; R = 1024; C = 1024; bo = 0;
    tx = loc & 15; ty = loc >> 4;
  }
  __shared__ float tile[64][65];
  const int c0 = tx * 64, r0 = ty * 64, t = threadIdx.x;
  {
    const int r = t >> 4, c4 = (t & 15) * 4;
#pragma unroll
    for (int p = 0; p < 4; p++) {
      const int rr = p * 16 + r;
      const float4 v = *(const float4*)(src + bo + (size_t)(r0 + rr) * C + c0 + c4);
      tile[rr][c4 + 0] = v.x; tile[rr][c4 + 1] = v.y;
      tile[rr][c4 + 2] = v.z; tile[rr][c4 + 3] = v.w;
    }
  }
  __syncthreads();
  {
    const int c = t >> 2, rb = (t & 3) * 16;
#pragma unroll
    for (int s = 0; s < 4; s++) {
      const int rr = rb + 4 * s;
      union { unsigned short u[4]; uint2 v; } pk;
#pragma unroll
      for (int i = 0; i < 4; i++) pk.u[i] = f2bf(tile[rr + i][c]);
      *(uint2*)(dst + bo + (size_t)(c0 + c) * R + r0 + rr) = pk.v;
    }
  }
}

// ---------------------------------------------------------------------------
// Phase 1: gate/up. Block tile M=128 x (128 G + 128 U cols), BK=32.
// 4 waves (2m x 2n); wave tile 64m x (64G + 64U).
// LDS dbuf: sA 2x[128x32], sB 2x[256x32] bf16 (48 KB). Single-barrier loop:
//   barrier -> prefetch(k+1 -> other buf) -> compute(k). Prefetch latency is
//   hidden behind compute; barrier at k+1 drains loads issued a full compute
//   section earlier.
// Swizzle: row = 4 chunks of 16B; logical chunk g stored at phys g^((r>>1)&3)
// -> all ds_read_b128 frag reads are 2-way bank aliased (free, m136). glds16
// stores are contiguous per instr (swizzle applied to SOURCE addresses).
// ---------------------------------------------------------------------------
__global__ __launch_bounds__(256, 2) void phase1_kernel(
    const unsigned short* __restrict__ Xb,
    const unsigned short* __restrict__ WgT,   // [16][512][1024]
    const unsigned short* __restrict__ WuT,   // [16][512][1024]
    const unsigned short* __restrict__ WsguT, // [2048][1024]
    const int* __restrict__ counts, const int* __restrict__ list,
    const float* __restrict__ wt,
    unsigned short* __restrict__ Hr,          // [4096][512] compact
    unsigned short* __restrict__ Hs) {        // [1024][1024]
  const int z = blockIdx.z, x = blockIdx.x, y = blockIdx.y;
  const bool routed = (z < NEXP);
  int cnt = 0, base = 0;
  if (routed) {
    if (x >= 4) return;                       // routed: 4 x-tiles of 128 I-cols
    cnt = counts[z];
    if (y * 128 >= cnt) return;
#pragma unroll
    for (int i = 0; i < NEXP; i++) base += (i < z) ? counts[i] : 0;
  }
  __shared__ __align__(16) unsigned short sA[2][128 * 32];
  __shared__ __align__(16) unsigned short sB[2][256 * 32];
  const int tid = threadIdx.x, w = tid >> 6, l = tid & 63;
  const int wm = w >> 1, wn = w & 1, m0 = y * 128;
  const int lg = ((l & 3) ^ ((l >> 3) & 3)) * 8;  // source chunk offset (elems)

  // A staging: 8 groups of 16 rows; wave w -> groups 2w,2w+1; lane covers
  // row grp*16+(l>>2), phys chunk l&3.
  const unsigned short* aP[2];
#pragma unroll
  for (int ii = 0; ii < 2; ii++) {
    const int r = (2 * w + ii) * 16 + (l >> 2);
    const unsigned short* row;
    if (routed) row = Xb + (size_t)list[z * 1024 + min(m0 + r, cnt - 1)] * HID;
    else        row = Xb + (size_t)(m0 + r) * HID;
    aP[ii] = row + lg;
  }
  // B staging: 16 groups; wave w -> groups 4w..4w+3. Rows 0-127: G, 128-255: U.
  const unsigned short* bP[4];
#pragma unroll
  for (int ii = 0; ii < 4; ii++) {
    const int R = (4 * w + ii) * 16 + (l >> 2);
    const int col = x * 128 + (R & 127);
    const unsigned short* row;
    if (routed)
      row = ((R >= 128) ? WuT : WgT) + ((size_t)z * MINTER + col) * HID;
    else
      row = WsguT + ((size_t)((R >= 128) ? SINTER : 0) + col) * HID;
    bP[ii] = row + lg;
  }

  int aoff[4], boff[4];
#pragma unroll
  for (int i = 0; i < 4; i++) {
    const int m = wm * 64 + 16 * i + (l & 15);
    aoff[i] = m * 32 + (((l >> 4) ^ ((m >> 1) & 3)) * 8);
  }
#pragma unroll
  for (int j = 0; j < 4; j++) {
    const int n = wn * 64 + 16 * j + (l & 15);
    boff[j] = n * 32 + (((l >> 4) ^ ((n >> 1) & 3)) * 8);
  }

  f32x4 accG[4][4], accU[4][4];
#pragma unroll
  for (int i = 0; i < 4; i++)
#pragma unroll
    for (int j = 0; j < 4; j++) {
      accG[i][j] = (f32x4){0.f, 0.f, 0.f, 0.f};
      accU[i][j] = (f32x4){0.f, 0.f, 0.f, 0.f};
    }

  auto stage = [&](int k0, int bi) {
    unsigned short* A = sA[bi]; unsigned short* B = sB[bi];
#pragma unroll
    for (int ii = 0; ii < 2; ii++) glds16(aP[ii] + k0, A + (2 * w + ii) * 512);
#pragma unroll
    for (int ii = 0; ii < 4; ii++) glds16(bP[ii] + k0, B + (4 * w + ii) * 512);
  };

  stage(0, 0);
  const int steps = HID / 32;
  for (int s = 0; s < steps; s++) {
    __syncthreads();                       // drains stage(s); buf s&1 ready
    if (s + 1 < steps) stage((s + 1) * 32, (s + 1) & 1);
    const unsigned short* A = sA[s & 1];
    const unsigned short* B = sB[s & 1];
    bf16x8 af[4];
#pragma unroll
    for (int i = 0; i < 4; i++) af[i] = as_bf16x8(*(const ushort8*)(A + aoff[i]));
#pragma unroll
    for (int j = 0; j < 4; j++) {
      const bf16x8 gf = as_bf16x8(*(const ushort8*)(B + boff[j]));
      const bf16x8 uf = as_bf16x8(*(const ushort8*)(B + 128 * 32 + boff[j]));
#pragma unroll
      for (int i = 0; i < 4; i++) {
        accG[i][j] = __builtin_amdgcn_mfma_f32_16x16x32_bf16(af[i], gf, accG[i][j], 0, 0, 0);
        accU[i][j] = __builtin_amdgcn_mfma_f32_16x16x32_bf16(af[i], uf, accU[i][j], 0, 0, 0);
      }
    }
  }

  // epilogue: C/D map col=lane&15, row=(lane>>4)*4+reg
#pragma unroll
  for (int i = 0; i < 4; i++)
#pragma unroll
    for (int r = 0; r < 4; r++) {
      const int row = wm * 64 + 16 * i + (l >> 4) * 4 + r;
      const int grow = m0 + row;
      if (routed) {
        if (grow < cnt) {
          const float wrow = wt[z * 1024 + grow];
#pragma unroll
          for (int j = 0; j < 4; j++) {
            const int col = x * 128 + wn * 64 + 16 * j + (l & 15);
            const float h = silu(accG[i][j][r]) * accU[i][j][r] * wrow;
            Hr[(size_t)(base + grow) * MINTER + col] = f2bf(h);
          }
        }
      } else {
#pragma unroll
        for (int j = 0; j < 4; j++) {
          const int col = x * 128 + wn * 64 + 16 * j + (l & 15);
          const float h = silu(accG[i][j][r]) * accU[i][j][r];
          Hs[(size_t)grow * SINTER + col] = f2bf(h);
        }
      }
    }
}

// ---------------------------------------------------------------------------
// Phase 2: down-proj. Block tile M=128 x N=256, BK=32, wave tile 64x128.
// Routed (z<16): K=512, bf16 stores to compact Rout. Shared (z==16): K=1024,
// fp32 stores to out. Same single-barrier dbuf loop.
// ---------------------------------------------------------------------------
__global__ __launch_bounds__(256, 2) void phase2_kernel(
    const unsigned short* __restrict__ Hr, const unsigned short* __restrict__ Hs,
    const unsigned short* __restrict__ WdT,  // [16][1024][512]
    const unsigned short* __restrict__ WsdT, // [1024][1024]
    const int* __restrict__ counts,
    unsigned short* __restrict__ Rout,       // [4096][1024] bf16 compact
    float* __restrict__ out) {               // [1024][1024]
  const int z = blockIdx.z, x = blockIdx.x, y = blockIdx.y;
  const bool routed = (z < NEXP);
  int cnt = 0, base = 0, kdim;
  if (routed) {
    cnt = counts[z];
    if (y * 128 >= cnt) return;
#pragma unroll
    for (int i = 0; i < NEXP; i++) base += (i < z) ? counts[i] : 0;
    kdim = MINTER;
  } else {
    kdim = SINTER;
  }
  __shared__ __align__(16) unsigned short sA[2][128 * 32];
  __shared__ __align__(16) unsigned short sB[2][256 * 32];
  const int tid = threadIdx.x, w = tid >> 6, l = tid & 63;
  const int wm = w >> 1, wn = w & 1, m0 = y * 128;
  const int lg = ((l & 3) ^ ((l >> 3) & 3)) * 8;

  const unsigned short* aP[2];
#pragma unroll
  for (int ii = 0; ii < 2; ii++) {
    const int r = (2 * w + ii) * 16 + (l >> 2);
    const unsigned short* row;
    if (routed) row = Hr + (size_t)(base + min(m0 + r, cnt - 1)) * MINTER;
    else        row = Hs + (size_t)(m0 + r) * SINTER;
    aP[ii] = row + lg;
  }
  const unsigned short* bP[4];
#pragma unroll
  for (int ii = 0; ii < 4; ii++) {
    const int R = (4 * w + ii) * 16 + (l >> 2);
    const int col = x * 256 + R;
    const unsigned short* row =
        routed ? (WdT + ((size_t)z * HID + col) * MINTER)
               : (WsdT + (size_t)col * SINTER);
    bP[ii] = row + lg;
  }

  int aoff[4], boff[8];
#pragma unroll
  for (int i = 0; i < 4; i++) {
    const int m = wm * 64 + 16 * i + (l & 15);
    aoff[i] = m * 32 + (((l >> 4) ^ ((m >> 1) & 3)) * 8);
  }
#pragma unroll
  for (int j = 0; j < 8; j++) {
    const int n = wn * 128 + 16 * j + (l & 15);
    boff[j] = n * 32 + (((l >> 4) ^ ((n >> 1) & 3)) * 8);
  }

  f32x4 acc[4][8];
#pragma unroll
  for (int i = 0; i < 4; i++)
#pragma unroll
    for (int j = 0; j < 8; j++) acc[i][j] = (f32x4){0.f, 0.f, 0.f, 0.f};

  auto stage = [&](int k0, int bi) {
    unsigned short* A = sA[bi]; unsigned short* B = sB[bi];
#pragma unroll
    for (int ii = 0; ii < 2; ii++) glds16(aP[ii] + k0, A + (2 * w + ii) * 512);
#pragma unroll
    for (int ii = 0; ii < 4; ii++) glds16(bP[ii] + k0, B + (4 * w + ii) * 512);
  };

  stage(0, 0);
  const int steps = kdim / 32;
  for (int s = 0; s < steps; s++) {
    __syncthreads();
    if (s + 1 < steps) stage((s + 1) * 32, (s + 1) & 1);
    const unsigned short* A = sA[s & 1];
    const unsigned short* B = sB[s & 1];
    bf16x8 af[4];
#pragma unroll
    for (int i = 0; i < 4; i++) af[i] = as_bf16x8(*(const ushort8*)(A + aoff[i]));
#pragma unroll
    for (int j = 0; j < 8; j++) {
      const bf16x8 bfv = as_bf16x8(*(const ushort8*)(B + boff[j]));
#pragma unroll
      for (int i = 0; i < 4; i++)
        acc[i][j] = __builtin_amdgcn_mfma_f32_16x16x32_bf16(af[i], bfv, acc[i][j], 0, 0, 0);
    }
  }

#pragma unroll
  for (int i = 0; i < 4; i++)
#pragma unroll
    for (int r = 0; r < 4; r++) {
      const int row = wm * 64 + 16 * i + (l >> 4) * 4 + r;
      const int grow = m0 + row;
      if (routed) {
        if (grow < cnt) {
#pragma unroll
          for (int j = 0; j < 8; j++) {
            const int col = x * 256 + wn * 128 + 16 * j + (l & 15);
            Rout[(size_t)(base + grow) * HID + col] = f2bf(acc[i][j][r]);
          }
        }
      } else {
#pragma unroll
        for (int j = 0; j < 8; j++) {
          const int col = x * 256 + wn * 128 + 16 * j + (l & 15);
          out[(size_t)grow * HID + col] = acc[i][j][r];
        }
      }
    }
}

// ------------- combine: out[t] += sum_k Rout[base[e_k]+pos_k] (bf16) -------
__global__ __launch_bounds__(256) void combine_kernel(
    const unsigned short* __restrict__ Rout, const int* __restrict__ counts,
    const int* __restrict__ tIdx, float* __restrict__ out) {
  __shared__ int sb[NEXP];
  if (threadIdx.x == 0) {
    int s = 0;
#pragma unroll
    for (int e = 0; e < NEXP; e++) { sb[e] = s; s += counts[e]; }
  }
  __syncthreads();
  const int t = blockIdx.x, c4 = threadIdx.x * 4;
  float4 o = *(const float4*)(out + (size_t)t * HID + c4);
#pragma unroll
  for (int k = 0; k < TOPK; k++) {
    const int v = tIdx[t * TOPK + k];
    const int row = sb[v >> 10] + (v & 1023);
    const uint2 rv = *(const uint2*)(Rout + (size_t)row * HID + c4);
    o.x += bfu2f(rv.x & 0xffffu); o.y += bfu2f(rv.x >> 16);
    o.z += bfu2f(rv.y & 0xffffu); o.w += bfu2f(rv.y >> 16);
  }
  *(float4*)(out + (size_t)t * HID + c4) = o;
}

// ---------------------------------------------------------------------------
extern "C" void kernel_launch(void* const* d_in, const int* in_sizes, int n_in,
                              void* d_out, int out_size, void* d_ws, size_t ws_size,
                              hipStream_t stream) {
  const float* x      = (const float*)d_in[0];
  const float* rw     = (const float*)d_in[1];
  const float* w_gate = (const float*)d_in[2];
  const float* w_up   = (const float*)d_in[3];
  const float* w_down = (const float*)d_in[4];
  const float* ws_gu  = (const float*)d_in[5];
  const float* ws_dn  = (const float*)d_in[6];
  float* out = (float*)d_out;
  char* ws = (char*)d_ws;

  int*   counts = (int*)  (ws + OFF_COUNTS);
  int*   list   = (int*)  (ws + OFF_LIST);
  float* wtbuf  = (float*)(ws + OFF_WT);
  int*   tIdx   = (int*)  (ws + OFF_TIDX);
  unsigned short* Xb    = (unsigned short*)(ws + OFF_XB);
  unsigned short* Hs    = (unsigned short*)(ws + OFF_HS);
  unsigned short* Hr    = (unsigned short*)(ws + OFF_HR);
  unsigned short* WgT   = (unsigned short*)(ws + OFF_WGT);
  unsigned short* WuT   = (unsigned short*)(ws + OFF_WUT);
  unsigned short* WdT   = (unsigned short*)(ws + OFF_WDT);
  unsigned short* WsguT = (unsigned short*)(ws + OFF_WSGUT);
  unsigned short* WsdT  = (unsigned short*)(ws + OFF_WSDT);
  unsigned short* Rout  = (unsigned short*)(ws + OFF_ROUT);

  init_kernel<<<1, 64, 0, stream>>>(counts);
  router_kernel<<<T_TOK, 64, 0, stream>>>(x, rw, counts, list, wtbuf, tIdx, Xb);
  transpose_all_kernel<<<6912, 256, 0, stream>>>(
      w_gate, w_up, w_down, ws_gu, ws_dn, WgT, WuT, WdT, WsguT, WsdT);
  phase1_kernel<<<dim3(8, 8, 17), 256, 0, stream>>>(
      Xb, WgT, WuT, WsguT, counts, list, wtbuf, Hr, Hs);
  phase2_kernel<<<dim3(4, 8, 17), 256, 0, stream>>>(
      Hr, Hs, WdT, WsdT, counts, Rout, out);
  combine_kernel<<<T_TOK, 256, 0, stream>>>(Rout, counts, tIdx, out);
  (void)in_sizes; (void)n_in; (void)out_size; (void)ws_size;
}